// Round 4
// baseline (226.801 us; speedup 1.0000x reference)
//
#include <hip/hip_runtime.h>
#include <hip/hip_bf16.h>

// Problem constants (fixed by setup_inputs)
#define Bq 2
#define Lq 2048
#define BLq (Bq*Lq)          // 4096
#define KNB 48
#define NA 14
#define NTOK 21
#define NRBF 16
#define POSD 16
#define EOUT 128
#define KDIM 416             // 16 pos + 400 rbf = 13*32
#define ASTRIDE 424          // padded row stride (bf16 elems), 848B = 53*16B
#define ESTRIDE 132          // padded fp32 row stride for LN staging
#define E_ELEMS (BLq*KNB*EOUT)   // 25165824

typedef __attribute__((ext_vector_type(8))) short short8;
typedef __attribute__((ext_vector_type(4))) float f32x4;

__device__ __forceinline__ unsigned short bf16_rn(float x) {
    unsigned int u = __float_as_uint(x);
    unsigned int r = (u + 0x7fffu + ((u >> 16) & 1u)) >> 16;
    return (unsigned short)r;
}

// ---------------- Kernel P: fused [xall (16 blocks)] + [W_e pack (208 blocks)] ----
__global__ void prep_kernel(const float* __restrict__ X, const int* __restrict__ S,
                            const int* __restrict__ table, const float* __restrict__ mask,
                            const float* __restrict__ We,
                            float* __restrict__ Xall, float4* __restrict__ CA4,
                            short* __restrict__ Wp) {
    int bid = blockIdx.x;
    if (bid < 16) {
        int t = bid * 256 + threadIdx.x;
        if (t >= BLq) return;
        int s = S[t];
        float bb[4][3];
#pragma unroll
        for (int a = 0; a < 4; ++a) {
            int ia = table[s * 4 + a];
#pragma unroll
            for (int d = 0; d < 3; ++d) bb[a][d] = X[(t * NA + ia) * 3 + d];
        }
        float b1[3], b2[3], nr[3];
#pragma unroll
        for (int d = 0; d < 3; ++d) { b1[d] = bb[0][d] - bb[1][d]; b2[d] = bb[2][d] - bb[1][d]; }
        nr[0] = b1[1] * b2[2] - b1[2] * b2[1];
        nr[1] = b1[2] * b2[0] - b1[0] * b2[2];
        nr[2] = b1[0] * b2[1] - b1[1] * b2[0];
#pragma unroll
        for (int a = 0; a < 4; ++a)
#pragma unroll
            for (int d = 0; d < 3; ++d) Xall[t * 15 + a * 3 + d] = bb[a][d];
#pragma unroll
        for (int d = 0; d < 3; ++d) {
            float xv = 0.58273431f * nr[d] + (-0.56802827f) * b1[d] + (-0.54067466f) * b2[d] + bb[1][d];
            Xall[t * 15 + 12 + d] = xv;
        }
        CA4[t] = make_float4(bb[1][0], bb[1][1], bb[1][2], mask[t]);
    } else {
        // pack W_e (416x128) into MFMA B-fragment order, bf16
        int t = (bid - 16) * 256 + threadIdx.x;
        if (t >= 13 * 8 * 64 * 8) return;
        int j = t & 7;
        int lane = (t >> 3) & 63;
        int nt = (t >> 9) & 7;
        int kt = t >> 12;
        int k = kt * 32 + (lane >> 4) * 8 + j;
        int n = nt * 16 + (lane & 15);
        Wp[t] = (short)bf16_rn(We[k * 128 + n]);
    }
}

// ---------------- Fused kernel: 48-NN radix select -> features -> MFMA -> LayerNorm ----
// key = (u64(f32_bits(D_adj)) << 16) | idx  -- keys distinct, ascending order
// matches lax.top_k(-D_adj) tie-breaking (lower index first on equal D).
__global__ __launch_bounds__(256) void fused_kernel(
    const float4* __restrict__ CA4, const float* __restrict__ Xall,
    const int* __restrict__ ridx, const float* __restrict__ Wpos,
    const float* __restrict__ bpos, const short* __restrict__ Wp,
    const float* __restrict__ lng, const float* __restrict__ lnb,
    float* __restrict__ out, float* __restrict__ out_idx) {
    __shared__ __align__(16) unsigned short Asm[KNB * ASTRIDE];  // 40704 B; overlays: hist/buf early, Esm late
    __shared__ float Dsm[KNB * 25];
    __shared__ float Xq[16];
    __shared__ float Xn[KNB * 15];
    __shared__ int offs[KNB];
    __shared__ int eidxs[KNB];
    __shared__ unsigned int nacc;
    __shared__ int sh_bin, sh_excl, sh_cnt;

    unsigned int* hist = (unsigned int*)Asm;                       // bytes [0,1024)
    unsigned long long* buf = (unsigned long long*)(Asm + 1024);   // bytes [2048,3072)

    int bl = blockIdx.x;
    int b = bl >> 11;
    int base = b << 11;
    int tid = threadIdx.x;

    // ---- phase T0: distance keys (bit-exact vs numpy: no FMA contraction) ----
    float4 q = CA4[bl];
    unsigned long long key[8];
#pragma unroll
    for (int i = 0; i < 8; ++i) {
        int j = tid + (i << 8);
        float4 c = CA4[base + j];
        float dx = __fsub_rn(q.x, c.x);
        float dy = __fsub_rn(q.y, c.y);
        float dz = __fsub_rn(q.z, c.z);
        float s = __fadd_rn(__fadd_rn(__fmul_rn(dx, dx), __fmul_rn(dy, dy)), __fmul_rn(dz, dz));
        float D = __fsqrt_rn(__fadd_rn(s, 1e-6f));
        float m2 = __fmul_rn(q.w, c.w);
        float Dadj = __fadd_rn(__fmul_rn(D, m2), __fmul_rn(__fsub_rn(1.0f, m2), 1000000.0f));
        key[i] = (((unsigned long long)__float_as_uint(Dadj)) << 16) | (unsigned int)j;
    }
    if (tid < 15) Xq[tid] = Xall[bl * 15 + tid];

    // ---- phase T1: MSB-first radix select ----
    unsigned long long prefix = 0;
    int need = 48, cnt = 0, shift = 40;
    for (;;) {
        hist[tid] = 0;
        __syncthreads();
#pragma unroll
        for (int i = 0; i < 8; ++i)
            if ((key[i] >> (shift + 8)) == prefix)
                atomicAdd(&hist[(unsigned int)((key[i] >> shift) & 255ull)], 1u);
        __syncthreads();
        if (tid < 64) {
            unsigned int h0 = hist[4 * tid + 0], h1 = hist[4 * tid + 1];
            unsigned int h2 = hist[4 * tid + 2], h3 = hist[4 * tid + 3];
            unsigned int s4 = h0 + h1 + h2 + h3;
            unsigned int incl = s4;
#pragma unroll
            for (int o = 1; o < 64; o <<= 1) {
                unsigned int v = __shfl_up(incl, o);
                if (tid >= o) incl += v;
            }
            unsigned int excl = incl - s4;
            if ((int)excl < need && need <= (int)incl) {   // exactly one lane
                unsigned int cb = excl;
                unsigned int hh[4] = {h0, h1, h2, h3};
                int bsel = 3;
#pragma unroll
                for (int bb2 = 0; bb2 < 4; ++bb2) {
                    if ((int)(cb + hh[bb2]) >= need) { bsel = bb2; break; }
                    cb += hh[bb2];
                }
                sh_bin = 4 * tid + bsel;
                sh_excl = (int)cb;
                sh_cnt = (int)hh[bsel];
            }
        }
        __syncthreads();
        prefix = (prefix << 8) | (unsigned long long)(unsigned int)sh_bin;
        need -= sh_excl;
        cnt = sh_cnt;
        if (cnt <= 80 || shift == 0) break;
        shift -= 8;
    }

    // ---- phase T2: collect <=127 candidates, rank by all-pairs count ----
    if (tid == 0) nacc = 0;
    __syncthreads();
#pragma unroll
    for (int i = 0; i < 8; ++i) {
        if ((key[i] >> shift) <= prefix) {
            unsigned int p = atomicAdd(&nacc, 1u);
            if (p < 128) buf[p] = key[i];
        }
    }
    __syncthreads();
    unsigned int m = nacc;
    if (tid < 128 && tid >= m) buf[tid] = ~0ULL;
    __syncthreads();
    if (tid < 128) {
        unsigned long long k = buf[tid];
        int rank = 0;
        for (int u = 0; u < 128; ++u) rank += (buf[u] < k) ? 1 : 0;
        if (rank < KNB) {
            int j = (int)(k & 0xffffull);
            eidxs[rank] = j;
            out_idx[bl * KNB + rank] = (float)j;
        }
    }
    __syncthreads();   // eidxs ready; hist/buf region dead from here on

    // ---- phase 0+1: rel-pos offsets + neighbor atom staging ----
    if (tid < KNB) {
        int j = eidxs[tid];
        int off = ridx[bl] - ridx[base + j] + 32;
        offs[tid] = min(max(off, 0), 64);
    }
    for (int f = tid; f < KNB * 15; f += 256) {
        int k = f / 15, d = f - k * 15;
        Xn[f] = Xall[(base + eidxs[k]) * 15 + d];
    }
    __syncthreads();

    // ---- phase 2: 48*25 pairwise atom distances ----
    for (int f = tid; f < KNB * 25; f += 256) {
        int k = f / 25, p = f - k * 25;
        int a = p / 5, c = p - a * 5;
        float dx = Xq[a * 3 + 0] - Xn[k * 15 + c * 3 + 0];
        float dy = Xq[a * 3 + 1] - Xn[k * 15 + c * 3 + 1];
        float dz = Xq[a * 3 + 2] - Xn[k * 15 + c * 3 + 2];
        Dsm[f] = sqrtf(dx * dx + dy * dy + dz * dz + 1e-6f);
    }
    __syncthreads();

    // ---- phase 3a: pos columns (0..15), packed bf16x2 ----
#pragma unroll
    for (int i = 0; i < 2; ++i) {
        int t = tid + (i << 8);
        if (t < KNB * 8) {
            int k = t >> 3, cd = (t & 7) << 1;
            int off = offs[k];
            float v0 = Wpos[off * 16 + cd] + bpos[cd];
            float v1 = Wpos[off * 16 + cd + 1] + bpos[cd + 1];
            *(__hip_bfloat162*)&Asm[k * ASTRIDE + cd] = __float22bfloat162_rn(make_float2(v0, v1));
        }
    }
    // ---- phase 3b: RBF columns (16..415); exp(-((D-mu)/1.25)^2) = exp2(-((D-mu)*s1)^2) ----
    if (tid < 200) {
        int pr = tid >> 3;                 // atom-pair 0..24
        int r0 = (tid & 7) << 1;           // rbf index 0,2,..,14
        const float s1 = 0.96089795f;
        const float dlt = 1.28119727f;     // (20/15)*s1
        float c0 = (2.0f + 1.3333333f * (float)r0) * s1;
        unsigned short* arow = Asm + 16 + (tid << 1);
        const float* drow = Dsm + pr;
        for (int k = 0; k < KNB; ++k) {
            float D = drow[k * 25];
            float u0 = __builtin_fmaf(D, s1, -c0);
            float u1 = u0 - dlt;
            float v0 = __builtin_amdgcn_exp2f(-(u0 * u0));
            float v1 = __builtin_amdgcn_exp2f(-(u1 * u1));
            *(__hip_bfloat162*)(arow + k * ASTRIDE) = __float22bfloat162_rn(make_float2(v0, v1));
        }
    }
    __syncthreads();

    // ---- phase 4: MFMA. wave w -> n-tiles {2w,2w+1}, m-tiles 0..2 ----
    int w = tid >> 6, lane = tid & 63;
    int quad = lane >> 4, lr = lane & 15;
    f32x4 acc[3][2];
#pragma unroll
    for (int mt = 0; mt < 3; ++mt)
#pragma unroll
        for (int nt = 0; nt < 2; ++nt) acc[mt][nt] = (f32x4){0.f, 0.f, 0.f, 0.f};

    for (int kt = 0; kt < 13; ++kt) {
        short8 bf0 = *(const short8*)(Wp + (((kt * 8 + 2 * w + 0) * 64 + lane) << 3));
        short8 bf1 = *(const short8*)(Wp + (((kt * 8 + 2 * w + 1) * 64 + lane) << 3));
#pragma unroll
        for (int mt = 0; mt < 3; ++mt) {
            short8 af = *(const short8*)(&Asm[(mt * 16 + lr) * ASTRIDE + kt * 32 + quad * 8]);
            acc[mt][0] = __builtin_amdgcn_mfma_f32_16x16x32_bf16(af, bf0, acc[mt][0], 0, 0, 0);
            acc[mt][1] = __builtin_amdgcn_mfma_f32_16x16x32_bf16(af, bf1, acc[mt][1], 0, 0, 0);
        }
    }
    __syncthreads();   // all A reads done before overlaying Esm

    // ---- phase 5: stage pre-LN E in LDS (overlay on Asm) ----
    float* Esm = (float*)Asm;
#pragma unroll
    for (int mt = 0; mt < 3; ++mt)
#pragma unroll
        for (int ntl = 0; ntl < 2; ++ntl) {
            int col = (2 * w + ntl) * 16 + lr;
#pragma unroll
            for (int r = 0; r < 4; ++r) {
                int row = mt * 16 + quad * 4 + r;
                Esm[row * ESTRIDE + col] = acc[mt][ntl][r];
            }
        }
    __syncthreads();

    // ---- phase 6: LayerNorm per edge row (wave per row), one-pass var ----
    float g0 = lng[lane], g1 = lng[lane + 64];
    float bb0 = lnb[lane], bb1 = lnb[lane + 64];
    for (int r = w; r < KNB; r += 4) {
        float v0 = Esm[r * ESTRIDE + lane];
        float v1 = Esm[r * ESTRIDE + lane + 64];
        float s = v0 + v1;
        float qq = __builtin_fmaf(v0, v0, v1 * v1);
#pragma unroll
        for (int o = 32; o > 0; o >>= 1) { s += __shfl_xor(s, o); qq += __shfl_xor(qq, o); }
        float mean = s * 0.0078125f;
        float var = __builtin_fmaf(-mean, mean, qq * 0.0078125f);
        float inv = rsqrtf(var + 1e-5f);
        float a0 = inv * g0, a1 = inv * g1;
        int ob = (bl * KNB + r) * EOUT;
        out[ob + lane] = __builtin_fmaf(v0 - mean, a0, bb0);
        out[ob + lane + 64] = __builtin_fmaf(v1 - mean, a1, bb1);
    }
}

extern "C" void kernel_launch(void* const* d_in, const int* in_sizes, int n_in,
                              void* d_out, int out_size, void* d_ws, size_t ws_size,
                              hipStream_t stream) {
    const float* X    = (const float*)d_in[0];
    // d_in[1] = X_m (unused by reference)
    const int*   S    = (const int*)d_in[2];
    const int*   ridx = (const int*)d_in[3];
    const float* mask = (const float*)d_in[4];
    const int*   tab  = (const int*)d_in[5];
    const float* Wpos = (const float*)d_in[6];
    const float* bpos = (const float*)d_in[7];
    const float* We   = (const float*)d_in[8];
    const float* lng  = (const float*)d_in[9];
    const float* lnb  = (const float*)d_in[10];
    float* out = (float*)d_out;

    char* ws = (char*)d_ws;
    float*  Xall = (float*)ws;                        // 4096*15*4 = 245760 B
    short*  Wp   = (short*)(ws + 245760);             // 53248*2   = 106496 B
    float4* CA4  = (float4*)(ws + 245760 + 106496);   // 4096*16   = 65536 B

    prep_kernel<<<224, 256, 0, stream>>>(X, S, tab, mask, We, Xall, CA4, Wp);
    fused_kernel<<<BLq, 256, 0, stream>>>(CA4, Xall, ridx, Wpos, bpos, Wp, lng, lnb,
                                          out, out + E_ELEMS);
}